// Round 6
// baseline (62075.842 us; speedup 1.0000x reference)
//
#include <hip/hip_runtime.h>
#include <cstdint>
#include <cstddef>

#define ZONEOUT 0.1f

typedef __attribute__((ext_vector_type(8))) short bf16x8;
typedef __attribute__((ext_vector_type(4))) float f32x4;
typedef __attribute__((ext_vector_type(4))) unsigned short u16x4;
typedef __attribute__((ext_vector_type(8))) unsigned short u16x8;
typedef __attribute__((ext_vector_type(4))) float float4_;

static constexpr int BB = 16;    // batch
static constexpr int TT = 4096;  // time
static constexpr int DD = 256;   // model dim
static constexpr int UU = 256;   // units
static constexpr int GG = 768;   // 3*UU
static constexpr int STR = 282;  // u16 row stride, 141 dw (odd) -> <=3-way banks on b128 reads
static constexpr int UTS = 70;   // Utail u16 row stride, 35 dw (odd) -> <=2-way banks

__device__ __forceinline__ unsigned short f2bf(float f) {
  unsigned int u = __builtin_bit_cast(unsigned int, f);
  u = u + 0x7fffu + ((u >> 16) & 1u);
  return (unsigned short)(u >> 16);
}
__device__ __forceinline__ float bf2f(unsigned short s) {
  unsigned int u = ((unsigned int)s) << 16;
  return __builtin_bit_cast(float, u);
}
__device__ __forceinline__ float sigm(float x) {
  float e = __builtin_amdgcn_exp2f(-1.4426950408889634f * x);
  return __builtin_amdgcn_rcpf(1.0f + e);
}
__device__ __forceinline__ float tanh_(float x) {
  float e = __builtin_amdgcn_exp2f(2.8853900817779268f * x);
  return 1.0f - 2.0f * __builtin_amdgcn_rcpf(1.0f + e);
}

// Workgroup barrier WITHOUT vmcnt(0) drain: LDS-visibility only.
// Safe here: all cross-wave hazards in the scan are LDS; global y/xg are
// partitioned per wave identically for loads and stores.
__device__ __forceinline__ void wg_barrier_lds() {
  asm volatile("s_waitcnt lgkmcnt(0)\n\ts_barrier" ::: "memory");
}

// dst[n*K + k] = (bf16) src[k*N + n]   (src: [K][N] fp32, dst: [N][K] bf16)
__global__ void transpose_cast_kernel(const float* __restrict__ src,
                                      unsigned short* __restrict__ dst,
                                      int K, int N) {
  int idx = blockIdx.x * blockDim.x + threadIdx.x;
  int total = K * N;
  if (idx < total) {
    int k = idx / N, n = idx - k * N;          // read-coalesced
    dst[(size_t)n * K + k] = f2bf(src[idx]);
  }
}

// xg[m][u][slot] = (In @ W)[m][g] + b_in[g];  g = slot*256 + u.  64x64 tile.
__launch_bounds__(256, 2)
__global__ void gates_gemm_kernel(const float* __restrict__ In,          // [M][256] fp32
                                  const unsigned short* __restrict__ Wt, // [768][256] bf16 (transposed)
                                  const float* __restrict__ bin,         // [768]
                                  unsigned short* __restrict__ xgp) {    // [M][256][4] bf16
  __shared__ unsigned short Asm[64 * STR];
  __shared__ unsigned short Bsm[64 * STR];
  const int m0 = blockIdx.x * 64;
  const int n0 = blockIdx.y * 64;
  const int tid = threadIdx.x;
  {
    int row = tid >> 2, cb = (tid & 3) * 64;
    const float* src = In + (size_t)(m0 + row) * DD + cb;
#pragma unroll
    for (int i = 0; i < 16; ++i) {
      float4_ v = *(const float4_*)(src + i * 4);
      u16x4 o;
      o.x = f2bf(v.x); o.y = f2bf(v.y); o.z = f2bf(v.z); o.w = f2bf(v.w);
      *(u16x4*)(&Asm[row * STR + cb + i * 4]) = o;
    }
  }
  {
#pragma unroll
    for (int i = 0; i < 8; ++i) {
      int c = i * 256 + tid;
      int row = c >> 5, part = c & 31;
      u16x8 v = *(const u16x8*)(Wt + (size_t)(n0 + row) * 256 + part * 8);
      *(u16x8*)(&Bsm[row * STR + part * 8]) = v;
    }
  }
  __syncthreads();
  const int w = tid >> 6, l = tid & 63, lr = l & 15, lg = l >> 4;
  f32x4 acc[4] = {};
#pragma unroll
  for (int k0 = 0; k0 < 8; ++k0) {
    bf16x8 a = *(const bf16x8*)(&Asm[(16 * w + lr) * STR + 32 * k0 + 8 * lg]);
#pragma unroll
    for (int ti = 0; ti < 4; ++ti) {
      bf16x8 b = *(const bf16x8*)(&Bsm[(16 * ti + lr) * STR + 32 * k0 + 8 * lg]);
      acc[ti] = __builtin_amdgcn_mfma_f32_16x16x32_bf16(a, b, acc[ti], 0, 0, 0);
    }
  }
#pragma unroll
  for (int ti = 0; ti < 4; ++ti) {
    int gcol = n0 + 16 * ti + lr;
    float bias = bin[gcol];
    int u = gcol & 255, slot = gcol >> 8;
#pragma unroll
    for (int r = 0; r < 4; ++r) {
      int m = m0 + 16 * w + 4 * lg + r;
      xgp[(size_t)m * 1024 + u * 4 + slot] = f2bf(acc[ti][r] + bias);
    }
  }
}

// In-place dense head: y[m][:] = (bf16)y[m][:] @ Wd + bd.  64-row blocks, BN=256.
__launch_bounds__(256, 2)
__global__ void head_gemm_kernel(float* __restrict__ y,                   // [M][256] fp32, in-place
                                 const unsigned short* __restrict__ Wdt,  // [256][256] bf16 (transposed)
                                 const float* __restrict__ bd) {          // [256]
  __shared__ unsigned short Asm[64 * STR];
  const int m0 = blockIdx.x * 64;
  const int tid = threadIdx.x;
  {
    int row = tid >> 2, cb = (tid & 3) * 64;
    const float* src = y + (size_t)(m0 + row) * UU + cb;
#pragma unroll
    for (int i = 0; i < 16; ++i) {
      float4_ v = *(const float4_*)(src + i * 4);
      u16x4 o;
      o.x = f2bf(v.x); o.y = f2bf(v.y); o.z = f2bf(v.z); o.w = f2bf(v.w);
      *(u16x4*)(&Asm[row * STR + cb + i * 4]) = o;
    }
  }
  __syncthreads();
  const int w = tid >> 6, l = tid & 63, lr = l & 15, lg = l >> 4;
  f32x4 acc[16] = {};
#pragma unroll
  for (int k0 = 0; k0 < 8; ++k0) {
    bf16x8 a = *(const bf16x8*)(&Asm[(16 * w + lr) * STR + 32 * k0 + 8 * lg]);
#pragma unroll
    for (int ti = 0; ti < 16; ++ti) {
      bf16x8 b = *(const bf16x8*)(Wdt + (size_t)(16 * ti + lr) * 256 + 32 * k0 + 8 * lg);
      acc[ti] = __builtin_amdgcn_mfma_f32_16x16x32_bf16(a, b, acc[ti], 0, 0, 0);
    }
  }
#pragma unroll
  for (int ti = 0; ti < 16; ++ti) {
    int n = 16 * ti + lr;
    float bias = bd[n];
#pragma unroll
    for (int r = 0; r < 4; ++r) {
      int m = m0 + 16 * w + 4 * lg + r;
      y[(size_t)m * DD + n] = acc[ti][r] + bias;
    }
  }
}

// Sequential GRU scan, one workgroup, 16 waves (1024 threads).
// Wave w owns units [16w, 16w+16): ufr = 3 gates x 6 k-steps = 72 VGPRs,
// fitting the default 128-VGPR budget (4 waves/SIMD) with NO spills by
// construction. U k-steps 6..7 live in LDS (bank-conflict-free stride).
__global__ void __attribute__((amdgpu_flat_work_group_size(1024, 1024)))
gru_scan_kernel(const unsigned short* __restrict__ xgp, // [B*T][256][4] bf16 (xz,xr,xh,pad)
                const unsigned short* __restrict__ Ut,  // [768][256] bf16 (transposed)
                const float* __restrict__ brec,         // [768] = b[1]
                const float* __restrict__ h0,           // [256]
                float* __restrict__ y,                  // [B][T][256] fp32
                int resid) {
  __shared__ unsigned short Utail[GG * UTS];     // k 192..255, 70 u16 stride
  __shared__ unsigned short Hsm[2][BB * STR];    // double-buffered h (bf16)

  const int tid = threadIdx.x;
  const int w = tid >> 6;       // wave 0..15
  const int l = tid & 63;
  const int lr = l & 15;
  const int lg = l >> 4;
  const int u = 16 * w + lr;    // this lane's unit column

  // Stage U k-tail into LDS (768 rows x 64 bf16)
#pragma unroll
  for (int i = 0; i < 6; ++i) {
    int c = i * 1024 + tid;
    int row = c >> 3, part = c & 7;
    u16x8 v = *(const u16x8*)(Ut + (size_t)row * 256 + 192 + part * 8);
    *(u16x8*)(&Utail[row * UTS + part * 8]) = v;
  }

  // Register-resident U fragments (k-steps 0..5): 3 gates x 6 = 72 VGPRs.
  f32x4 ufr[3][6];
  float bias[3];
#pragma unroll
  for (int g = 0; g < 3; ++g) {
    int n = g * 256 + u;
    bias[g] = brec[n];
#pragma unroll
    for (int k0 = 0; k0 < 6; ++k0)
      ufr[g][k0] = *(const f32x4*)(Ut + (size_t)n * 256 + 32 * k0 + 8 * lg);
  }
  // Opaque pin: prevents re-sinking of the loop-invariant loads.
#pragma unroll
  for (int g = 0; g < 3; ++g)
#pragma unroll
    for (int k0 = 0; k0 < 6; ++k0)
      asm volatile("" : "+v"(ufr[g][k0]));

  // h init (broadcast h0 across batch) into buffer 0
  float hprev[4];
  {
    float hv = h0[u];
#pragma unroll
    for (int r = 0; r < 4; ++r) {
      hprev[r] = hv;
      int b = 4 * lg + r;
      Hsm[0][b * STR + u] = f2bf(hv);
    }
  }

  // Prefetch xg(0)
  u16x4 xv[4];
#pragma unroll
  for (int r = 0; r < 4; ++r) {
    int b = 4 * lg + r;
    xv[r] = *(const u16x4*)(xgp + ((size_t)b * TT) * 1024 + u * 4);
  }
  wg_barrier_lds();

  for (int t = 0; t < TT; ++t) {
    const unsigned short* cur = &Hsm[t & 1][0];
    unsigned short* nxt = &Hsm[(t + 1) & 1][0];

    // Residual prefetch (window = MFMA phase)
    float ypref[4];
    if (resid) {
#pragma unroll
      for (int r = 0; r < 4; ++r) {
        int b = 4 * lg + r;
        ypref[r] = y[((size_t)b * TT + t) * UU + u];
      }
    }

    // rg = h @ U + b_rec (bias in acc init)
    f32x4 acc[3];
#pragma unroll
    for (int g = 0; g < 3; ++g) {
      float bv = bias[g];
      acc[g] = (f32x4){bv, bv, bv, bv};
    }
#pragma unroll
    for (int k0 = 0; k0 < 8; ++k0) {
      bf16x8 a = *(const bf16x8*)(&cur[lr * STR + 32 * k0 + 8 * lg]);
      if (k0 < 6) {
#pragma unroll
        for (int g = 0; g < 3; ++g)
          acc[g] = __builtin_amdgcn_mfma_f32_16x16x32_bf16(
              a, __builtin_bit_cast(bf16x8, ufr[g][k0]), acc[g], 0, 0, 0);
      } else {
#pragma unroll
        for (int g = 0; g < 3; ++g) {
          int n = g * 256 + u;
          bf16x8 bfr = *(const bf16x8*)(&Utail[n * UTS + (k0 - 6) * 32 + 8 * lg]);
          acc[g] = __builtin_amdgcn_mfma_f32_16x16x32_bf16(a, bfr, acc[g], 0, 0, 0);
        }
      }
    }
    // NO barrier: gate phase writes `nxt`, MFMA read `cur` (disjoint buffers).

    const int tn = (t + 1 < TT) ? t + 1 : t;  // prefetch target (last discarded)
    // Gate math in registers; lane owns (b = 4*lg+r, u)
#pragma unroll
    for (int r = 0; r < 4; ++r) {
      int b = 4 * lg + r;
      u16x4 xvv = xv[r];
      // reload just-freed xv regs with xg(t+1): latency hides under barrier+next MFMA
      xv[r] = *(const u16x4*)(xgp + ((size_t)b * TT + tn) * 1024 + u * 4);
      float xz = bf2f(xvv.x), xr = bf2f(xvv.y), xh = bf2f(xvv.z);
      float h = hprev[r];
      float z = sigm(xz + acc[0][r]);
      float rg = sigm(xr + acc[1][r]);
      float hh = tanh_(xh + rg * acc[2][r]);
      float cand = hh + z * (h - hh);
      float hnew = cand + ZONEOUT * (h - cand);
      hprev[r] = hnew;
      nxt[b * STR + u] = f2bf(hnew);
      float ov = cand;
      if (resid) ov += ypref[r];
      y[((size_t)b * TT + t) * UU + u] = ov;  // store stays in flight (no vmcnt drain)
    }
    wg_barrier_lds();  // nxt visible to all waves
  }
}

extern "C" void kernel_launch(void* const* d_in, const int* in_sizes, int n_in,
                              void* d_out, int out_size, void* d_ws, size_t ws_size,
                              hipStream_t stream) {
  const float* x = (const float*)d_in[0];
  const float* W[3]  = {(const float*)d_in[1], (const float*)d_in[5], (const float*)d_in[9]};
  const float* Um[3] = {(const float*)d_in[2], (const float*)d_in[6], (const float*)d_in[10]};
  const float* bm[3] = {(const float*)d_in[3], (const float*)d_in[7], (const float*)d_in[11]};
  const float* h0m[3] = {(const float*)d_in[4], (const float*)d_in[8], (const float*)d_in[12]};
  const float* Wd = (const float*)d_in[13];
  const float* bd = (const float*)d_in[14];
  float* out = (float*)d_out;

  char* ws = (char*)d_ws;
  unsigned short* xgp = (unsigned short*)ws;  // [65536][256][4] bf16 = 134,217,728 B
  size_t off = (size_t)65536 * 1024 * 2;
  unsigned short* Ut[3];
  unsigned short* Wt[3];
  for (int l = 0; l < 3; ++l) { Ut[l] = (unsigned short*)(ws + off); off += (size_t)768 * 256 * 2; }
  for (int l = 0; l < 3; ++l) { Wt[l] = (unsigned short*)(ws + off); off += (size_t)768 * 256 * 2; }
  unsigned short* Wdt = (unsigned short*)(ws + off); off += (size_t)256 * 256 * 2;

  const int tgrid = (768 * 256 + 255) / 256;
  for (int l = 0; l < 3; ++l) {
    hipLaunchKernelGGL(transpose_cast_kernel, dim3(tgrid), dim3(256), 0, stream, Um[l], Ut[l], 256, 768);
    hipLaunchKernelGGL(transpose_cast_kernel, dim3(tgrid), dim3(256), 0, stream, W[l], Wt[l], 256, 768);
  }
  hipLaunchKernelGGL(transpose_cast_kernel, dim3((256 * 256 + 255) / 256), dim3(256), 0, stream,
                     Wd, Wdt, 256, 256);

  for (int l = 0; l < 3; ++l) {
    const float* in_l = (l == 0) ? x : out;
    hipLaunchKernelGGL(gates_gemm_kernel, dim3(1024, 12), dim3(256), 0, stream,
                       in_l, Wt[l], bm[l], xgp);
    hipLaunchKernelGGL(gru_scan_kernel, dim3(1), dim3(1024), 0, stream,
                       xgp, Ut[l], bm[l] + 768, h0m[l], out, l ? 1 : 0);
  }
  hipLaunchKernelGGL(head_gemm_kernel, dim3(1024), dim3(256), 0, stream, out, Wdt, bd);
}

// Round 7
// 56957.056 us; speedup vs baseline: 1.0899x; 1.0899x over previous
//
#include <hip/hip_runtime.h>
#include <cstdint>
#include <cstddef>

#define ZONEOUT 0.1f

typedef __attribute__((ext_vector_type(8))) short bf16x8;
typedef __attribute__((ext_vector_type(4))) float f32x4;
typedef __attribute__((ext_vector_type(4))) unsigned short u16x4;
typedef __attribute__((ext_vector_type(8))) unsigned short u16x8;
typedef __attribute__((ext_vector_type(4))) float float4_;

static constexpr int BB = 16;    // batch
static constexpr int TT = 4096;  // time
static constexpr int DD = 256;   // model dim
static constexpr int UU = 256;   // units
static constexpr int GG = 768;   // 3*UU
static constexpr int STR = 282;  // u16 row stride, 141 dw (odd) -> low bank aliasing on b128 reads

__device__ __forceinline__ unsigned short f2bf(float f) {
  unsigned int u = __builtin_bit_cast(unsigned int, f);
  u = u + 0x7fffu + ((u >> 16) & 1u);
  return (unsigned short)(u >> 16);
}
__device__ __forceinline__ float bf2f(unsigned short s) {
  unsigned int u = ((unsigned int)s) << 16;
  return __builtin_bit_cast(float, u);
}
__device__ __forceinline__ float sigm(float x) {
  float e = __builtin_amdgcn_exp2f(-1.4426950408889634f * x);
  return __builtin_amdgcn_rcpf(1.0f + e);
}
__device__ __forceinline__ float tanh_(float x) {
  float e = __builtin_amdgcn_exp2f(2.8853900817779268f * x);
  return 1.0f - 2.0f * __builtin_amdgcn_rcpf(1.0f + e);
}

// Workgroup barrier WITHOUT vmcnt(0) drain: LDS-visibility only.
// Safe: cross-wave hazards in the scan are LDS-only; global y/xg are
// partitioned per wave identically for loads and stores.
__device__ __forceinline__ void wg_barrier_lds() {
  asm volatile("s_waitcnt lgkmcnt(0)\n\ts_barrier" ::: "memory");
}

// dst[n*K + k] = (bf16) src[k*N + n]   (src: [K][N] fp32, dst: [N][K] bf16)
__global__ void transpose_cast_kernel(const float* __restrict__ src,
                                      unsigned short* __restrict__ dst,
                                      int K, int N) {
  int idx = blockIdx.x * blockDim.x + threadIdx.x;
  int total = K * N;
  if (idx < total) {
    int k = idx / N, n = idx - k * N;          // read-coalesced
    dst[(size_t)n * K + k] = f2bf(src[idx]);
  }
}

// xg[m][u][slot] = (In @ W)[m][g] + b_in[g] (+ b_rec[g] for z,r slots).
// g = slot*256 + u.  64x64 tile.
__launch_bounds__(256, 2)
__global__ void gates_gemm_kernel(const float* __restrict__ In,          // [M][256] fp32
                                  const unsigned short* __restrict__ Wt, // [768][256] bf16 (transposed)
                                  const float* __restrict__ bin,         // [768]
                                  const float* __restrict__ brec,        // [768] = b[1]
                                  unsigned short* __restrict__ xgp) {    // [M][256][4] bf16
  __shared__ unsigned short Asm[64 * STR];
  __shared__ unsigned short Bsm[64 * STR];
  const int m0 = blockIdx.x * 64;
  const int n0 = blockIdx.y * 64;
  const int tid = threadIdx.x;
  {
    int row = tid >> 2, cb = (tid & 3) * 64;
    const float* src = In + (size_t)(m0 + row) * DD + cb;
#pragma unroll
    for (int i = 0; i < 16; ++i) {
      float4_ v = *(const float4_*)(src + i * 4);
      u16x4 o;
      o.x = f2bf(v.x); o.y = f2bf(v.y); o.z = f2bf(v.z); o.w = f2bf(v.w);
      *(u16x4*)(&Asm[row * STR + cb + i * 4]) = o;
    }
  }
  {
#pragma unroll
    for (int i = 0; i < 8; ++i) {
      int c = i * 256 + tid;
      int row = c >> 5, part = c & 31;
      u16x8 v = *(const u16x8*)(Wt + (size_t)(n0 + row) * 256 + part * 8);
      *(u16x8*)(&Bsm[row * STR + part * 8]) = v;
    }
  }
  __syncthreads();
  const int w = tid >> 6, l = tid & 63, lr = l & 15, lg = l >> 4;
  f32x4 acc[4] = {};
#pragma unroll
  for (int k0 = 0; k0 < 8; ++k0) {
    bf16x8 a = *(const bf16x8*)(&Asm[(16 * w + lr) * STR + 32 * k0 + 8 * lg]);
#pragma unroll
    for (int ti = 0; ti < 4; ++ti) {
      bf16x8 b = *(const bf16x8*)(&Bsm[(16 * ti + lr) * STR + 32 * k0 + 8 * lg]);
      acc[ti] = __builtin_amdgcn_mfma_f32_16x16x32_bf16(a, b, acc[ti], 0, 0, 0);
    }
  }
#pragma unroll
  for (int ti = 0; ti < 4; ++ti) {
    int gcol = n0 + 16 * ti + lr;
    int u = gcol & 255, slot = gcol >> 8;
    float bias = bin[gcol] + (slot < 2 ? brec[gcol] : 0.0f);  // fold b_rec for z,r
#pragma unroll
    for (int r = 0; r < 4; ++r) {
      int m = m0 + 16 * w + 4 * lg + r;
      xgp[(size_t)m * 1024 + u * 4 + slot] = f2bf(acc[ti][r] + bias);
    }
  }
}

// In-place dense head: y[m][:] = (bf16)y[m][:] @ Wd + bd.  64-row blocks, BN=256.
__launch_bounds__(256, 2)
__global__ void head_gemm_kernel(float* __restrict__ y,                   // [M][256] fp32, in-place
                                 const unsigned short* __restrict__ Wdt,  // [256][256] bf16 (transposed)
                                 const float* __restrict__ bd) {          // [256]
  __shared__ unsigned short Asm[64 * STR];
  const int m0 = blockIdx.x * 64;
  const int tid = threadIdx.x;
  {
    int row = tid >> 2, cb = (tid & 3) * 64;
    const float* src = y + (size_t)(m0 + row) * UU + cb;
#pragma unroll
    for (int i = 0; i < 16; ++i) {
      float4_ v = *(const float4_*)(src + i * 4);
      u16x4 o;
      o.x = f2bf(v.x); o.y = f2bf(v.y); o.z = f2bf(v.z); o.w = f2bf(v.w);
      *(u16x4*)(&Asm[row * STR + cb + i * 4]) = o;
    }
  }
  __syncthreads();
  const int w = tid >> 6, l = tid & 63, lr = l & 15, lg = l >> 4;
  f32x4 acc[16] = {};
#pragma unroll
  for (int k0 = 0; k0 < 8; ++k0) {
    bf16x8 a = *(const bf16x8*)(&Asm[(16 * w + lr) * STR + 32 * k0 + 8 * lg]);
#pragma unroll
    for (int ti = 0; ti < 16; ++ti) {
      bf16x8 b = *(const bf16x8*)(Wdt + (size_t)(16 * ti + lr) * 256 + 32 * k0 + 8 * lg);
      acc[ti] = __builtin_amdgcn_mfma_f32_16x16x32_bf16(a, b, acc[ti], 0, 0, 0);
    }
  }
#pragma unroll
  for (int ti = 0; ti < 16; ++ti) {
    int n = 16 * ti + lr;
    float bias = bd[n];
#pragma unroll
    for (int r = 0; r < 4; ++r) {
      int m = m0 + 16 * w + 4 * lg + r;
      y[(size_t)m * DD + n] = acc[ti][r] + bias;
    }
  }
}

// Sequential GRU scan, one workgroup, 8 waves (512 threads).
// Wave w owns units [32w, 32w+32).  The ENTIRE U for this wave's columns
// (2 tri x 3 gates x 8 k-steps = 192 regs) is pinned into AGPRs: gfx950 MFMA
// reads B directly from AGPRs, AGPRs don't count against the 128-VGPR budget
// the allocator insists on, and the loop-invariant U never touches LDS.
// LDS holds only the double-buffered h (18 KB).
__global__ void __attribute__((amdgpu_flat_work_group_size(512, 512)))
gru_scan_kernel(const unsigned short* __restrict__ xgp, // [B*T][256][4] bf16 (xz,xr,xh,pad)
                const unsigned short* __restrict__ Ut,  // [768][256] bf16 (transposed)
                const float* __restrict__ brec,         // [768] = b[1]
                const float* __restrict__ h0,           // [256]
                float* __restrict__ y,                  // [B][T][256] fp32
                int resid) {
  __shared__ unsigned short Hsm[2][BB * STR];    // double-buffered h (bf16)

  const int tid = threadIdx.x;
  const int w = tid >> 6;
  const int l = tid & 63;
  const int lr = l & 15;
  const int lg = l >> 4;

  // Full U fragments for this wave's (z,r,h) triples -> pinned to AGPRs.
  f32x4 ufr[2][3][8];
  float bias_h[2];
#pragma unroll
  for (int tri = 0; tri < 2; ++tri) {
    int u = 32 * w + 16 * tri + lr;
    bias_h[tri] = brec[512 + u];
#pragma unroll
    for (int g = 0; g < 3; ++g) {
      int n = g * 256 + u;
#pragma unroll
      for (int k0 = 0; k0 < 8; ++k0)
        ufr[tri][g][k0] = *(const f32x4*)(Ut + (size_t)n * 256 + 32 * k0 + 8 * lg);
    }
  }
#pragma unroll
  for (int tri = 0; tri < 2; ++tri)
#pragma unroll
    for (int g = 0; g < 3; ++g)
#pragma unroll
      for (int k0 = 0; k0 < 8; ++k0)
        asm volatile("" : "+a"(ufr[tri][g][k0]));  // AGPR pin

  // h init (broadcast h0 across batch) into buffer 0
  float hprev[2][4];
#pragma unroll
  for (int tri = 0; tri < 2; ++tri) {
    int u = 32 * w + 16 * tri + lr;
    float hv = h0[u];
#pragma unroll
    for (int r = 0; r < 4; ++r) {
      hprev[tri][r] = hv;
      int b = 4 * lg + r;
      Hsm[0][b * STR + u] = f2bf(hv);
    }
  }

  // Prefetch xg(0)
  u16x4 xv[2][4];
#pragma unroll
  for (int tri = 0; tri < 2; ++tri) {
    int u = 32 * w + 16 * tri + lr;
#pragma unroll
    for (int r = 0; r < 4; ++r) {
      int b = 4 * lg + r;
      xv[tri][r] = *(const u16x4*)(xgp + ((size_t)b * TT) * 1024 + u * 4);
    }
  }
  wg_barrier_lds();

  for (int t = 0; t < TT; ++t) {
    const unsigned short* cur = &Hsm[t & 1][0];
    unsigned short* nxt = &Hsm[(t + 1) & 1][0];

    // Residual prefetch (window = MFMA phase)
    float ypref[2][4];
    if (resid) {
#pragma unroll
      for (int tri = 0; tri < 2; ++tri) {
        int u = 32 * w + 16 * tri + lr;
#pragma unroll
        for (int r = 0; r < 4; ++r) {
          int b = 4 * lg + r;
          ypref[tri][r] = y[((size_t)b * TT + t) * UU + u];
        }
      }
    }

    // rg = h @ U   (z,r biases folded into xg; h bias applied in gate phase)
    f32x4 acc[2][3] = {};
#pragma unroll
    for (int k0 = 0; k0 < 8; ++k0) {
      bf16x8 a = *(const bf16x8*)(&cur[lr * STR + 32 * k0 + 8 * lg]);
#pragma unroll
      for (int tri = 0; tri < 2; ++tri)
#pragma unroll
        for (int g = 0; g < 3; ++g)
          acc[tri][g] = __builtin_amdgcn_mfma_f32_16x16x32_bf16(
              a, __builtin_bit_cast(bf16x8, ufr[tri][g][k0]), acc[tri][g], 0, 0, 0);
    }
    // NO barrier: gate phase writes `nxt`, MFMA read `cur` (disjoint buffers).

    const int tn = (t + 1 < TT) ? t + 1 : t;  // prefetch target (last discarded)
    // Gate math in registers; lane owns (b = 4*lg+r, u = 32w+16tri+lr)
#pragma unroll
    for (int tri = 0; tri < 2; ++tri) {
      int u = 32 * w + 16 * tri + lr;
#pragma unroll
      for (int r = 0; r < 4; ++r) {
        int b = 4 * lg + r;
        u16x4 xvv = xv[tri][r];
        // reload just-freed xv regs with xg(t+1): latency hides under next MFMA
        xv[tri][r] = *(const u16x4*)(xgp + ((size_t)b * TT + tn) * 1024 + u * 4);
        float xz = bf2f(xvv.x), xr = bf2f(xvv.y), xh = bf2f(xvv.z);
        float h = hprev[tri][r];
        float z = sigm(xz + acc[tri][0][r]);
        float rg = sigm(xr + acc[tri][1][r]);
        float hh = tanh_(xh + rg * (acc[tri][2][r] + bias_h[tri]));
        float cand = hh + z * (h - hh);
        float hnew = cand + ZONEOUT * (h - cand);
        hprev[tri][r] = hnew;
        nxt[b * STR + u] = f2bf(hnew);
        float ov = cand;
        if (resid) ov += ypref[tri][r];
        y[((size_t)b * TT + t) * UU + u] = ov;  // store stays in flight
      }
    }
    wg_barrier_lds();  // nxt visible to all waves
  }
}

extern "C" void kernel_launch(void* const* d_in, const int* in_sizes, int n_in,
                              void* d_out, int out_size, void* d_ws, size_t ws_size,
                              hipStream_t stream) {
  const float* x = (const float*)d_in[0];
  const float* W[3]  = {(const float*)d_in[1], (const float*)d_in[5], (const float*)d_in[9]};
  const float* Um[3] = {(const float*)d_in[2], (const float*)d_in[6], (const float*)d_in[10]};
  const float* bm[3] = {(const float*)d_in[3], (const float*)d_in[7], (const float*)d_in[11]};
  const float* h0m[3] = {(const float*)d_in[4], (const float*)d_in[8], (const float*)d_in[12]};
  const float* Wd = (const float*)d_in[13];
  const float* bd = (const float*)d_in[14];
  float* out = (float*)d_out;

  char* ws = (char*)d_ws;
  unsigned short* xgp = (unsigned short*)ws;  // [65536][256][4] bf16 = 134,217,728 B
  size_t off = (size_t)65536 * 1024 * 2;
  unsigned short* Ut[3];
  unsigned short* Wt[3];
  for (int l = 0; l < 3; ++l) { Ut[l] = (unsigned short*)(ws + off); off += (size_t)768 * 256 * 2; }
  for (int l = 0; l < 3; ++l) { Wt[l] = (unsigned short*)(ws + off); off += (size_t)768 * 256 * 2; }
  unsigned short* Wdt = (unsigned short*)(ws + off); off += (size_t)256 * 256 * 2;

  const int tgrid = (768 * 256 + 255) / 256;
  for (int l = 0; l < 3; ++l) {
    hipLaunchKernelGGL(transpose_cast_kernel, dim3(tgrid), dim3(256), 0, stream, Um[l], Ut[l], 256, 768);
    hipLaunchKernelGGL(transpose_cast_kernel, dim3(tgrid), dim3(256), 0, stream, W[l], Wt[l], 256, 768);
  }
  hipLaunchKernelGGL(transpose_cast_kernel, dim3((256 * 256 + 255) / 256), dim3(256), 0, stream,
                     Wd, Wdt, 256, 256);

  for (int l = 0; l < 3; ++l) {
    const float* in_l = (l == 0) ? x : out;
    hipLaunchKernelGGL(gates_gemm_kernel, dim3(1024, 12), dim3(256), 0, stream,
                       in_l, Wt[l], bm[l], bm[l] + 768, xgp);
    hipLaunchKernelGGL(gru_scan_kernel, dim3(1), dim3(512), 0, stream,
                       xgp, Ut[l], bm[l] + 768, h0m[l], out, l ? 1 : 0);
  }
  hipLaunchKernelGGL(head_gemm_kernel, dim3(1024), dim3(256), 0, stream, out, Wdt, bd);
}

// Round 9
// 43007.144 us; speedup vs baseline: 1.4434x; 1.3244x over previous
//
#include <hip/hip_runtime.h>
#include <cstdint>
#include <cstddef>

#define ZONEOUT 0.1f

typedef __attribute__((ext_vector_type(8))) short bf16x8;
typedef __attribute__((ext_vector_type(4))) float f32x4;
typedef __attribute__((ext_vector_type(4))) unsigned short u16x4;
typedef __attribute__((ext_vector_type(8))) unsigned short u16x8;
typedef __attribute__((ext_vector_type(4))) float float4_;

static constexpr int BB = 16;    // batch
static constexpr int TT = 4096;  // time
static constexpr int DD = 256;   // model dim
static constexpr int UU = 256;   // units
static constexpr int GG = 768;   // 3*UU
static constexpr int STR = 280;  // u16 row stride: 560B = 35*16 (b128-aligned), ~2-way banks
static constexpr int UTS = 72;   // Utail u16 row stride: 144B = 9*16 (aligned), ~2-way banks

__device__ __forceinline__ unsigned short f2bf(float f) {
  unsigned int u = __builtin_bit_cast(unsigned int, f);
  u = u + 0x7fffu + ((u >> 16) & 1u);
  return (unsigned short)(u >> 16);
}
__device__ __forceinline__ float bf2f(unsigned short s) {
  unsigned int u = ((unsigned int)s) << 16;
  return __builtin_bit_cast(float, u);
}
__device__ __forceinline__ float sigm(float x) {
  float e = __builtin_amdgcn_exp2f(-1.4426950408889634f * x);
  return __builtin_amdgcn_rcpf(1.0f + e);
}
__device__ __forceinline__ float tanh_(float x) {
  float e = __builtin_amdgcn_exp2f(2.8853900817779268f * x);
  return 1.0f - 2.0f * __builtin_amdgcn_rcpf(1.0f + e);
}

// Workgroup barrier WITHOUT vmcnt(0) drain: LDS-visibility only.
// Safe: cross-wave hazards in the scan are LDS-only; global y/xg are
// partitioned per wave identically for loads and stores.
__device__ __forceinline__ void wg_barrier_lds() {
  asm volatile("s_waitcnt lgkmcnt(0)\n\ts_barrier" ::: "memory");
}

// dst[n*K + k] = (bf16) src[k*N + n]
__global__ void transpose_cast_kernel(const float* __restrict__ src,
                                      unsigned short* __restrict__ dst,
                                      int K, int N) {
  int idx = blockIdx.x * blockDim.x + threadIdx.x;
  int total = K * N;
  if (idx < total) {
    int k = idx / N, n = idx - k * N;
    dst[(size_t)n * K + k] = f2bf(src[idx]);
  }
}

// xg[m][u][slot] = (In @ W)[m][g] + b_in[g] (+ b_rec[g] for z,r).  Slot 3 unused.
__launch_bounds__(256, 2)
__global__ void gates_gemm_kernel(const float* __restrict__ In,          // [M][256] fp32
                                  const unsigned short* __restrict__ Wt, // [768][256] bf16
                                  const float* __restrict__ bin,         // [768]
                                  const float* __restrict__ brec,        // [768]
                                  unsigned short* __restrict__ xgp) {    // [M][256][4] bf16
  __shared__ unsigned short Asm[64 * STR];
  __shared__ unsigned short Bsm[64 * STR];
  const int m0 = blockIdx.x * 64;
  const int n0 = blockIdx.y * 64;
  const int tid = threadIdx.x;
  {
    int row = tid >> 2, cb = (tid & 3) * 64;
    const float* src = In + (size_t)(m0 + row) * DD + cb;
#pragma unroll
    for (int i = 0; i < 16; ++i) {
      float4_ v = *(const float4_*)(src + i * 4);
      u16x4 o;
      o.x = f2bf(v.x); o.y = f2bf(v.y); o.z = f2bf(v.z); o.w = f2bf(v.w);
      *(u16x4*)(&Asm[row * STR + cb + i * 4]) = o;
    }
  }
  {
#pragma unroll
    for (int i = 0; i < 8; ++i) {
      int c = i * 256 + tid;
      int row = c >> 5, part = c & 31;
      u16x8 v = *(const u16x8*)(Wt + (size_t)(n0 + row) * 256 + part * 8);
      *(u16x8*)(&Bsm[row * STR + part * 8]) = v;
    }
  }
  __syncthreads();
  const int w = tid >> 6, l = tid & 63, lr = l & 15, lg = l >> 4;
  f32x4 acc[4] = {};
#pragma unroll
  for (int k0 = 0; k0 < 8; ++k0) {
    bf16x8 a = *(const bf16x8*)(&Asm[(16 * w + lr) * STR + 32 * k0 + 8 * lg]);
#pragma unroll
    for (int ti = 0; ti < 4; ++ti) {
      bf16x8 b = *(const bf16x8*)(&Bsm[(16 * ti + lr) * STR + 32 * k0 + 8 * lg]);
      acc[ti] = __builtin_amdgcn_mfma_f32_16x16x32_bf16(a, b, acc[ti], 0, 0, 0);
    }
  }
#pragma unroll
  for (int ti = 0; ti < 4; ++ti) {
    int gcol = n0 + 16 * ti + lr;
    int u = gcol & 255, slot = gcol >> 8;
    float bias = bin[gcol] + (slot < 2 ? brec[gcol] : 0.0f);
#pragma unroll
    for (int r = 0; r < 4; ++r) {
      int m = m0 + 16 * w + 4 * lg + r;
      xgp[(size_t)m * 1024 + u * 4 + slot] = f2bf(acc[ti][r] + bias);
    }
  }
}

// In-place dense head: Y[m][:] = (bf16)Y[m][:] @ Wd + bd.
__launch_bounds__(256, 2)
__global__ void head_gemm_kernel(float* __restrict__ y,
                                 const unsigned short* __restrict__ Wdt,
                                 const float* __restrict__ bd) {
  __shared__ unsigned short Asm[64 * STR];
  const int m0 = blockIdx.x * 64;
  const int tid = threadIdx.x;
  {
    int row = tid >> 2, cb = (tid & 3) * 64;
    const float* src = y + (size_t)(m0 + row) * UU + cb;
#pragma unroll
    for (int i = 0; i < 16; ++i) {
      float4_ v = *(const float4_*)(src + i * 4);
      u16x4 o;
      o.x = f2bf(v.x); o.y = f2bf(v.y); o.z = f2bf(v.z); o.w = f2bf(v.w);
      *(u16x4*)(&Asm[row * STR + cb + i * 4]) = o;
    }
  }
  __syncthreads();
  const int w = tid >> 6, l = tid & 63, lr = l & 15, lg = l >> 4;
  f32x4 acc[16] = {};
#pragma unroll
  for (int k0 = 0; k0 < 8; ++k0) {
    bf16x8 a = *(const bf16x8*)(&Asm[(16 * w + lr) * STR + 32 * k0 + 8 * lg]);
#pragma unroll
    for (int ti = 0; ti < 16; ++ti) {
      bf16x8 b = *(const bf16x8*)(Wdt + (size_t)(16 * ti + lr) * 256 + 32 * k0 + 8 * lg);
      acc[ti] = __builtin_amdgcn_mfma_f32_16x16x32_bf16(a, b, acc[ti], 0, 0, 0);
    }
  }
#pragma unroll
  for (int ti = 0; ti < 16; ++ti) {
    int n = 16 * ti + lr;
    float bias = bd[n];
#pragma unroll
    for (int r = 0; r < 4; ++r) {
      int m = m0 + 16 * w + 4 * lg + r;
      y[(size_t)m * DD + n] = acc[ti][r] + bias;
    }
  }
}

// Sequential GRU scan, one workgroup, 8 waves (2 waves/SIMD -> 256-reg cap).
// U k0..5 in AGPRs (144 regs) + k6..7 in LDS; arch VGPR working set ~95-110,
// so arch+AGPR fits the 256 total budget (round-7 failed because 192+110 did
// not).  fp32 y path (resid read + fp32 store) kept for accuracy — round 8's
// bf16 residual accumulation tripled the output error past threshold.
__global__ void __attribute__((amdgpu_flat_work_group_size(512, 512)))
gru_scan_kernel(const unsigned short* __restrict__ xgp, // [B*T][256][4] bf16
                const unsigned short* __restrict__ Ut,  // [768][256] bf16
                const float* __restrict__ brec,         // [768]
                const float* __restrict__ h0,           // [256]
                float* __restrict__ y,                  // [B][T][256] fp32
                int resid) {
  __shared__ unsigned short Utail[GG * UTS];     // k 192..255
  __shared__ unsigned short Hsm[2][BB * STR];    // double-buffered h (bf16)

  const int tid = threadIdx.x;
  const int w = tid >> 6;
  const int l = tid & 63;
  const int lr = l & 15;
  const int lg = l >> 4;

  // Stage U k-tail (768 rows x 64 bf16)
#pragma unroll
  for (int i = 0; i < 12; ++i) {
    int c = i * 512 + tid;
    int row = c >> 3, part = c & 7;
    u16x8 v = *(const u16x8*)(Ut + (size_t)row * 256 + 192 + part * 8);
    *(u16x8*)(&Utail[row * UTS + part * 8]) = v;
  }

  // U fragments k0..5 -> AGPRs (36 x f32x4 = 144 regs); pin right after each
  // load to keep prologue arch-VGPR pressure low.
  f32x4 ufr[2][3][6];
  float bias_h[2];
#pragma unroll
  for (int tri = 0; tri < 2; ++tri) {
    int u = 32 * w + 16 * tri + lr;
    bias_h[tri] = brec[512 + u];
#pragma unroll
    for (int g = 0; g < 3; ++g) {
      int n = g * 256 + u;
#pragma unroll
      for (int k0 = 0; k0 < 6; ++k0) {
        ufr[tri][g][k0] = *(const f32x4*)(Ut + (size_t)n * 256 + 32 * k0 + 8 * lg);
        asm volatile("" : "+a"(ufr[tri][g][k0]));  // pin to AGPR
      }
    }
  }

  // h init
  float hprev[2][4];
#pragma unroll
  for (int tri = 0; tri < 2; ++tri) {
    int u = 32 * w + 16 * tri + lr;
    float hv = h0[u];
#pragma unroll
    for (int r = 0; r < 4; ++r) {
      hprev[tri][r] = hv;
      Hsm[0][(4 * lg + r) * STR + u] = f2bf(hv);
    }
  }

  // Per-lane xg byte offsets (tri adds 128B); y element offsets per (r,tri)
  unsigned xoff[4];
#pragma unroll
  for (int r = 0; r < 4; ++r)
    xoff[r] = (unsigned)((((4 * lg + r) * TT) * 1024 + (32 * w + lr) * 4) * 2);

  // Prefetch xg(0)
  u16x4 xv[2][4];
#pragma unroll
  for (int tri = 0; tri < 2; ++tri)
#pragma unroll
    for (int r = 0; r < 4; ++r)
      xv[tri][r] = *(const u16x4*)((const char*)xgp + xoff[r] + tri * 128);
  wg_barrier_lds();

  for (int t = 0; t < TT; ++t) {
    const unsigned short* cur = &Hsm[t & 1][0];
    unsigned short* nxt = &Hsm[(t + 1) & 1][0];

    // Residual prefetch (window = MFMA phase)
    float ypref[2][4];
    if (resid) {
#pragma unroll
      for (int tri = 0; tri < 2; ++tri) {
        int u = 32 * w + 16 * tri + lr;
#pragma unroll
        for (int r = 0; r < 4; ++r) {
          int b = 4 * lg + r;
          ypref[tri][r] = y[((size_t)b * TT + t) * UU + u];
        }
      }
    }

    // rg = h @ U  (z,r biases pre-folded into xg; h bias added below)
    f32x4 acc[2][3] = {};
#pragma unroll
    for (int k0 = 0; k0 < 8; ++k0) {
      bf16x8 a = *(const bf16x8*)(&cur[lr * STR + 32 * k0 + 8 * lg]);
      if (k0 < 6) {
#pragma unroll
        for (int tri = 0; tri < 2; ++tri)
#pragma unroll
          for (int g = 0; g < 3; ++g)
            acc[tri][g] = __builtin_amdgcn_mfma_f32_16x16x32_bf16(
                a, __builtin_bit_cast(bf16x8, ufr[tri][g][k0]), acc[tri][g], 0, 0, 0);
      } else {
#pragma unroll
        for (int tri = 0; tri < 2; ++tri)
#pragma unroll
          for (int g = 0; g < 3; ++g) {
            int n = g * 256 + 32 * w + 16 * tri + lr;
            bf16x8 bfr = *(const bf16x8*)(&Utail[n * UTS + (k0 - 6) * 32 + 8 * lg]);
            acc[tri][g] = __builtin_amdgcn_mfma_f32_16x16x32_bf16(a, bfr, acc[tri][g], 0, 0, 0);
          }
      }
    }
    // No barrier: gate phase writes nxt, MFMA read cur (disjoint buffers).

    const unsigned tnadd = (t < TT - 1) ? 2048u : 0u;
#pragma unroll
    for (int tri = 0; tri < 2; ++tri) {
      int u = 32 * w + 16 * tri + lr;
#pragma unroll
      for (int r = 0; r < 4; ++r) {
        int b = 4 * lg + r;
        u16x4 xvv = xv[tri][r];
        // reload just-freed xv regs with xg(t+1): latency hides under next MFMA
        xv[tri][r] = *(const u16x4*)((const char*)xgp + xoff[r] + tri * 128 + tnadd);
        float xz = bf2f(xvv.x), xr = bf2f(xvv.y), xh = bf2f(xvv.z);
        float h = hprev[tri][r];
        float z = sigm(xz + acc[tri][0][r]);
        float rg = sigm(xr + acc[tri][1][r]);
        float hh = tanh_(xh + rg * (acc[tri][2][r] + bias_h[tri]));
        float cand = hh + z * (h - hh);
        float hnew = cand + ZONEOUT * (h - cand);
        hprev[tri][r] = hnew;
        nxt[b * STR + u] = f2bf(hnew);
        float ov = cand;
        if (resid) ov += ypref[tri][r];
        y[((size_t)b * TT + t) * UU + u] = ov;  // fp32 store stays in flight
      }
    }
#pragma unroll
    for (int r = 0; r < 4; ++r) xoff[r] += 2048u;
    wg_barrier_lds();
  }
}

extern "C" void kernel_launch(void* const* d_in, const int* in_sizes, int n_in,
                              void* d_out, int out_size, void* d_ws, size_t ws_size,
                              hipStream_t stream) {
  const float* x = (const float*)d_in[0];
  const float* W[3]  = {(const float*)d_in[1], (const float*)d_in[5], (const float*)d_in[9]};
  const float* Um[3] = {(const float*)d_in[2], (const float*)d_in[6], (const float*)d_in[10]};
  const float* bm[3] = {(const float*)d_in[3], (const float*)d_in[7], (const float*)d_in[11]};
  const float* h0m[3] = {(const float*)d_in[4], (const float*)d_in[8], (const float*)d_in[12]};
  const float* Wd = (const float*)d_in[13];
  const float* bd = (const float*)d_in[14];
  float* Y = (float*)d_out;

  char* ws = (char*)d_ws;
  unsigned short* xgp = (unsigned short*)ws;  // [65536][256][4] bf16 = 134,217,728 B
  size_t off = (size_t)65536 * 1024 * 2;
  unsigned short* Ut[3];
  unsigned short* Wt[3];
  for (int l = 0; l < 3; ++l) { Ut[l] = (unsigned short*)(ws + off); off += (size_t)768 * 256 * 2; }
  for (int l = 0; l < 3; ++l) { Wt[l] = (unsigned short*)(ws + off); off += (size_t)768 * 256 * 2; }
  unsigned short* Wdt = (unsigned short*)(ws + off); off += (size_t)256 * 256 * 2;

  const int tgrid = (768 * 256 + 255) / 256;
  for (int l = 0; l < 3; ++l) {
    hipLaunchKernelGGL(transpose_cast_kernel, dim3(tgrid), dim3(256), 0, stream, Um[l], Ut[l], 256, 768);
    hipLaunchKernelGGL(transpose_cast_kernel, dim3(tgrid), dim3(256), 0, stream, W[l], Wt[l], 256, 768);
  }
  hipLaunchKernelGGL(transpose_cast_kernel, dim3((256 * 256 + 255) / 256), dim3(256), 0, stream,
                     Wd, Wdt, 256, 256);

  for (int l = 0; l < 3; ++l) {
    const float* in_l = (l == 0) ? x : Y;
    hipLaunchKernelGGL(gates_gemm_kernel, dim3(1024, 12), dim3(256), 0, stream,
                       in_l, Wt[l], bm[l], bm[l] + 768, xgp);
    hipLaunchKernelGGL(gru_scan_kernel, dim3(1), dim3(512), 0, stream,
                       xgp, Ut[l], bm[l] + 768, h0m[l], Y, l ? 1 : 0);
  }
  hipLaunchKernelGGL(head_gemm_kernel, dim3(1024), dim3(256), 0, stream, Y, Wdt, bd);
}

// Round 12
// 36418.530 us; speedup vs baseline: 1.7045x; 1.1809x over previous
//
#include <hip/hip_runtime.h>
#include <cstdint>
#include <cstddef>

#define ZONEOUT 0.1f

typedef __attribute__((ext_vector_type(8))) short bf16x8;
typedef __attribute__((ext_vector_type(4))) float f32x4;
typedef __attribute__((ext_vector_type(4))) unsigned short u16x4;
typedef __attribute__((ext_vector_type(8))) unsigned short u16x8;
typedef __attribute__((ext_vector_type(4))) float float4_;

static constexpr int BB = 16;    // batch
static constexpr int TT = 4096;  // time
static constexpr int DD = 256;   // model dim
static constexpr int UU = 256;   // units
static constexpr int GG = 768;   // 3*UU
static constexpr int STR = 280;  // u16 row stride: 560B = 35*16 (b128-aligned), ~2-way banks
static constexpr int UTS = 72;   // Utail u16 row stride: 144B = 9*16 (aligned)

__device__ __forceinline__ unsigned short f2bf(float f) {
  unsigned int u = __builtin_bit_cast(unsigned int, f);
  u = u + 0x7fffu + ((u >> 16) & 1u);
  return (unsigned short)(u >> 16);
}
__device__ __forceinline__ float bf2f(unsigned short s) {
  unsigned int u = ((unsigned int)s) << 16;
  return __builtin_bit_cast(float, u);
}
__device__ __forceinline__ float sigm(float x) {
  float e = __builtin_amdgcn_exp2f(-1.4426950408889634f * x);
  return __builtin_amdgcn_rcpf(1.0f + e);
}
__device__ __forceinline__ float tanh_(float x) {
  float e = __builtin_amdgcn_exp2f(2.8853900817779268f * x);
  return 1.0f - 2.0f * __builtin_amdgcn_rcpf(1.0f + e);
}

// Workgroup barrier WITHOUT vmcnt(0) drain: LDS-visibility only.
__device__ __forceinline__ void wg_barrier_lds() {
  asm volatile("s_waitcnt lgkmcnt(0)\n\ts_barrier" ::: "memory");
}

// dst[n*K + k] = (bf16) src[k*N + n]
__global__ void transpose_cast_kernel(const float* __restrict__ src,
                                      unsigned short* __restrict__ dst,
                                      int K, int N) {
  int idx = blockIdx.x * blockDim.x + threadIdx.x;
  int total = K * N;
  if (idx < total) {
    int k = idx / N, n = idx - k * N;
    dst[(size_t)n * K + k] = f2bf(src[idx]);
  }
}

// xg[m][u][slot] = (In @ W)[m][g] + b_in[g] (+ b_rec[g] for z,r).  Slot 3 unused.
__launch_bounds__(256, 2)
__global__ void gates_gemm_kernel(const float* __restrict__ In,          // [M][256] fp32
                                  const unsigned short* __restrict__ Wt, // [768][256] bf16
                                  const float* __restrict__ bin,         // [768]
                                  const float* __restrict__ brec,        // [768]
                                  unsigned short* __restrict__ xgp) {    // [M][256][4] bf16
  __shared__ unsigned short Asm[64 * STR];
  __shared__ unsigned short Bsm[64 * STR];
  const int m0 = blockIdx.x * 64;
  const int n0 = blockIdx.y * 64;
  const int tid = threadIdx.x;
  {
    int row = tid >> 2, cb = (tid & 3) * 64;
    const float* src = In + (size_t)(m0 + row) * DD + cb;
#pragma unroll
    for (int i = 0; i < 16; ++i) {
      float4_ v = *(const float4_*)(src + i * 4);
      u16x4 o;
      o.x = f2bf(v.x); o.y = f2bf(v.y); o.z = f2bf(v.z); o.w = f2bf(v.w);
      *(u16x4*)(&Asm[row * STR + cb + i * 4]) = o;
    }
  }
  {
#pragma unroll
    for (int i = 0; i < 8; ++i) {
      int c = i * 256 + tid;
      int row = c >> 5, part = c & 31;
      u16x8 v = *(const u16x8*)(Wt + (size_t)(n0 + row) * 256 + part * 8);
      *(u16x8*)(&Bsm[row * STR + part * 8]) = v;
    }
  }
  __syncthreads();
  const int w = tid >> 6, l = tid & 63, lr = l & 15, lg = l >> 4;
  f32x4 acc[4] = {};
#pragma unroll
  for (int k0 = 0; k0 < 8; ++k0) {
    bf16x8 a = *(const bf16x8*)(&Asm[(16 * w + lr) * STR + 32 * k0 + 8 * lg]);
#pragma unroll
    for (int ti = 0; ti < 4; ++ti) {
      bf16x8 b = *(const bf16x8*)(&Bsm[(16 * ti + lr) * STR + 32 * k0 + 8 * lg]);
      acc[ti] = __builtin_amdgcn_mfma_f32_16x16x32_bf16(a, b, acc[ti], 0, 0, 0);
    }
  }
#pragma unroll
  for (int ti = 0; ti < 4; ++ti) {
    int gcol = n0 + 16 * ti + lr;
    int u = gcol & 255, slot = gcol >> 8;
    float bias = bin[gcol] + (slot < 2 ? brec[gcol] : 0.0f);
#pragma unroll
    for (int r = 0; r < 4; ++r) {
      int m = m0 + 16 * w + 4 * lg + r;
      xgp[(size_t)m * 1024 + u * 4 + slot] = f2bf(acc[ti][r] + bias);
    }
  }
}

// In-place dense head: Y[m][:] = (bf16)Y[m][:] @ Wd + bd.
__launch_bounds__(256, 2)
__global__ void head_gemm_kernel(float* __restrict__ y,
                                 const unsigned short* __restrict__ Wdt,
                                 const float* __restrict__ bd) {
  __shared__ unsigned short Asm[64 * STR];
  const int m0 = blockIdx.x * 64;
  const int tid = threadIdx.x;
  {
    int row = tid >> 2, cb = (tid & 3) * 64;
    const float* src = y + (size_t)(m0 + row) * UU + cb;
#pragma unroll
    for (int i = 0; i < 16; ++i) {
      float4_ v = *(const float4_*)(src + i * 4);
      u16x4 o;
      o.x = f2bf(v.x); o.y = f2bf(v.y); o.z = f2bf(v.z); o.w = f2bf(v.w);
      *(u16x4*)(&Asm[row * STR + cb + i * 4]) = o;
    }
  }
  __syncthreads();
  const int w = tid >> 6, l = tid & 63, lr = l & 15, lg = l >> 4;
  f32x4 acc[16] = {};
#pragma unroll
  for (int k0 = 0; k0 < 8; ++k0) {
    bf16x8 a = *(const bf16x8*)(&Asm[(16 * w + lr) * STR + 32 * k0 + 8 * lg]);
#pragma unroll
    for (int ti = 0; ti < 16; ++ti) {
      bf16x8 b = *(const bf16x8*)(Wdt + (size_t)(16 * ti + lr) * 256 + 32 * k0 + 8 * lg);
      acc[ti] = __builtin_amdgcn_mfma_f32_16x16x32_bf16(a, b, acc[ti], 0, 0, 0);
    }
  }
#pragma unroll
  for (int ti = 0; ti < 16; ++ti) {
    int n = 16 * ti + lr;
    float bias = bd[n];
#pragma unroll
    for (int r = 0; r < 4; ++r) {
      int m = m0 + 16 * w + 4 * lg + r;
      y[(size_t)m * DD + n] = acc[ti][r] + bias;
    }
  }
}

// Sequential GRU scan: ONE workgroup of 256 threads = 4 waves, 1 wave/SIMD.
// The thread-count heuristic (1024->64, 512->128) gives 256-thr kernels a
// 256 arch-VGPR budget; with the unified 512-reg/wave file the AGPR side has
// its own 256.  Demand: 240 AGPR (U k0..4, "+a"-pinned) + ~200 arch
// (ufr5 48 + acc 48 + xv 32 + hprev/ypref 32 + misc).  ALL MFMAs are
// intrinsics — rounds 10/11 proved opaque-asm MFMA breaks the compiler's
// hazard insertion (VALU->MFMA SrcC wait states) and corrupts results.
__global__ void __attribute__((amdgpu_flat_work_group_size(256, 256), amdgpu_waves_per_eu(1, 1)))
gru_scan_kernel(const unsigned short* __restrict__ xgp, // [B*T][256][4] bf16
                const unsigned short* __restrict__ Ut,  // [768][256] bf16
                const float* __restrict__ brec,         // [768]
                const float* __restrict__ h0,           // [256]
                float* __restrict__ y,                  // [B][T][256] fp32
                int resid) {
  __shared__ unsigned short Utail[GG * UTS];     // k 192..255
  __shared__ unsigned short Hsm[2][BB * STR];    // double-buffered h (bf16)

  const int tid = threadIdx.x;
  const int w = tid >> 6;       // wave 0..3, owns units [64w, 64w+64)
  const int l = tid & 63;
  const int lr = l & 15;
  const int lg = l >> 4;

  // Stage U k-tail (768 rows x 64 bf16) with 256 threads
#pragma unroll
  for (int i = 0; i < 24; ++i) {
    int c = i * 256 + tid;
    int row = c >> 3, part = c & 7;
    u16x8 v = *(const u16x8*)(Ut + (size_t)row * 256 + 192 + part * 8);
    *(u16x8*)(&Utail[row * UTS + part * 8]) = v;
  }

  // U k0..4 -> AGPRs (60 x f32x4 = 240 regs); U k5 -> arch VGPRs (48).
  f32x4 ufr[4][3][5];
  f32x4 ufr5[4][3];
  float bias_h[4];
#pragma unroll
  for (int tri = 0; tri < 4; ++tri) {
    int u = 64 * w + 16 * tri + lr;
    bias_h[tri] = brec[512 + u];
#pragma unroll
    for (int g = 0; g < 3; ++g) {
      int n = g * 256 + u;
#pragma unroll
      for (int k0 = 0; k0 < 5; ++k0) {
        ufr[tri][g][k0] = *(const f32x4*)(Ut + (size_t)n * 256 + 32 * k0 + 8 * lg);
        asm volatile("" : "+a"(ufr[tri][g][k0]));  // place in AGPR (intrinsic reads AV-class)
      }
      ufr5[tri][g] = *(const f32x4*)(Ut + (size_t)n * 256 + 32 * 5 + 8 * lg);
      asm volatile("" : "+v"(ufr5[tri][g]));       // keep in arch VGPR
    }
  }

  // h init (broadcast h0) into buffer 0
  float hprev[4][4];
#pragma unroll
  for (int tri = 0; tri < 4; ++tri) {
    int u = 64 * w + 16 * tri + lr;
    float hv = h0[u];
#pragma unroll
    for (int r = 0; r < 4; ++r) {
      hprev[tri][r] = hv;
      Hsm[0][(4 * lg + r) * STR + u] = f2bf(hv);
    }
  }

  // Per-lane xg byte offsets (tri adds 128B)
  unsigned xoff[4];
#pragma unroll
  for (int r = 0; r < 4; ++r)
    xoff[r] = (unsigned)((((4 * lg + r) * TT) * 1024 + (64 * w + lr) * 4) * 2);

  // Prefetch xg(0)
  u16x4 xv[4][4];
#pragma unroll
  for (int tri = 0; tri < 4; ++tri)
#pragma unroll
    for (int r = 0; r < 4; ++r)
      xv[tri][r] = *(const u16x4*)((const char*)xgp + xoff[r] + tri * 128);
  wg_barrier_lds();

  for (int t = 0; t < TT; ++t) {
    const unsigned short* cur = &Hsm[t & 1][0];
    unsigned short* nxt = &Hsm[(t + 1) & 1][0];

    // Residual prefetch (window = MFMA phase)
    float ypref[4][4];
    if (resid) {
#pragma unroll
      for (int tri = 0; tri < 4; ++tri) {
        int u = 64 * w + 16 * tri + lr;
#pragma unroll
        for (int r = 0; r < 4; ++r) {
          int b = 4 * lg + r;
          ypref[tri][r] = y[((size_t)b * TT + t) * UU + u];
        }
      }
    }

    // rg = h @ U  (z,r biases pre-folded into xg; h bias added below).
    // All intrinsics: compiler owns every MFMA hazard.  B sources:
    // k0..4 AGPR-resident, k5 arch-VGPR, k6..7 LDS.
    f32x4 acc[4][3] = {};
#pragma unroll
    for (int k0 = 0; k0 < 5; ++k0) {
      bf16x8 a = *(const bf16x8*)(&cur[lr * STR + 32 * k0 + 8 * lg]);
#pragma unroll
      for (int tri = 0; tri < 4; ++tri)
#pragma unroll
        for (int g = 0; g < 3; ++g)
          acc[tri][g] = __builtin_amdgcn_mfma_f32_16x16x32_bf16(
              a, __builtin_bit_cast(bf16x8, ufr[tri][g][k0]), acc[tri][g], 0, 0, 0);
    }
    {
      bf16x8 a = *(const bf16x8*)(&cur[lr * STR + 32 * 5 + 8 * lg]);
#pragma unroll
      for (int tri = 0; tri < 4; ++tri)
#pragma unroll
        for (int g = 0; g < 3; ++g)
          acc[tri][g] = __builtin_amdgcn_mfma_f32_16x16x32_bf16(
              a, __builtin_bit_cast(bf16x8, ufr5[tri][g]), acc[tri][g], 0, 0, 0);
    }
#pragma unroll
    for (int k0 = 6; k0 < 8; ++k0) {
      bf16x8 a = *(const bf16x8*)(&cur[lr * STR + 32 * k0 + 8 * lg]);
#pragma unroll
      for (int tri = 0; tri < 4; ++tri)
#pragma unroll
        for (int g = 0; g < 3; ++g) {
          int n = g * 256 + 64 * w + 16 * tri + lr;
          bf16x8 bfr = *(const bf16x8*)(&Utail[n * UTS + (k0 - 6) * 32 + 8 * lg]);
          acc[tri][g] = __builtin_amdgcn_mfma_f32_16x16x32_bf16(a, bfr, acc[tri][g], 0, 0, 0);
        }
    }
    // No barrier: gate phase writes nxt, MFMA read cur (disjoint buffers).

    const unsigned tnadd = (t < TT - 1) ? 2048u : 0u;
#pragma unroll
    for (int tri = 0; tri < 4; ++tri) {
      int u = 64 * w + 16 * tri + lr;
#pragma unroll
      for (int r = 0; r < 4; ++r) {
        int b = 4 * lg + r;
        u16x4 xvv = xv[tri][r];
        // reload just-freed xv regs with xg(t+1): latency hides under next MFMA
        xv[tri][r] = *(const u16x4*)((const char*)xgp + xoff[r] + tri * 128 + tnadd);
        float xz = bf2f(xvv.x), xr = bf2f(xvv.y), xh = bf2f(xvv.z);
        float h = hprev[tri][r];
        float z = sigm(xz + acc[tri][0][r]);
        float rg = sigm(xr + acc[tri][1][r]);
        float hh = tanh_(xh + rg * (acc[tri][2][r] + bias_h[tri]));
        float cand = hh + z * (h - hh);
        float hnew = cand + ZONEOUT * (h - cand);
        hprev[tri][r] = hnew;
        nxt[b * STR + u] = f2bf(hnew);
        float ov = cand;
        if (resid) ov += ypref[tri][r];
        y[((size_t)b * TT + t) * UU + u] = ov;  // fp32 store stays in flight
      }
    }
#pragma unroll
    for (int r = 0; r < 4; ++r) xoff[r] += 2048u;
    wg_barrier_lds();
  }
}

extern "C" void kernel_launch(void* const* d_in, const int* in_sizes, int n_in,
                              void* d_out, int out_size, void* d_ws, size_t ws_size,
                              hipStream_t stream) {
  const float* x = (const float*)d_in[0];
  const float* W[3]  = {(const float*)d_in[1], (const float*)d_in[5], (const float*)d_in[9]};
  const float* Um[3] = {(const float*)d_in[2], (const float*)d_in[6], (const float*)d_in[10]};
  const float* bm[3] = {(const float*)d_in[3], (const float*)d_in[7], (const float*)d_in[11]};
  const float* h0m[3] = {(const float*)d_in[4], (const float*)d_in[8], (const float*)d_in[12]};
  const float* Wd = (const float*)d_in[13];
  const float* bd = (const float*)d_in[14];
  float* Y = (float*)d_out;

  char* ws = (char*)d_ws;
  unsigned short* xgp = (unsigned short*)ws;  // [65536][256][4] bf16 = 134,217,728 B
  size_t off = (size_t)65536 * 1024 * 2;
  unsigned short* Ut[3];
  unsigned short* Wt[3];
  for (int l = 0; l < 3; ++l) { Ut[l] = (unsigned short*)(ws + off); off += (size_t)768 * 256 * 2; }
  for (int l = 0; l < 3; ++l) { Wt[l] = (unsigned short*)(ws + off); off += (size_t)768 * 256 * 2; }
  unsigned short* Wdt = (unsigned short*)(ws + off); off += (size_t)256 * 256 * 2;

  const int tgrid = (768 * 256 + 255) / 256;
  for (int l = 0; l < 3; ++l) {
    hipLaunchKernelGGL(transpose_cast_kernel, dim3(tgrid), dim3(256), 0, stream, Um[l], Ut[l], 256, 768);
    hipLaunchKernelGGL(transpose_cast_kernel, dim3(tgrid), dim3(256), 0, stream, W[l], Wt[l], 256, 768);
  }
  hipLaunchKernelGGL(transpose_cast_kernel, dim3((256 * 256 + 255) / 256), dim3(256), 0, stream,
                     Wd, Wdt, 256, 256);

  for (int l = 0; l < 3; ++l) {
    const float* in_l = (l == 0) ? x : Y;
    hipLaunchKernelGGL(gates_gemm_kernel, dim3(1024, 12), dim3(256), 0, stream,
                       in_l, Wt[l], bm[l], bm[l] + 768, xgp);
    hipLaunchKernelGGL(gru_scan_kernel, dim3(1), dim3(256), 0, stream,
                       xgp, Ut[l], bm[l] + 768, h0m[l], Y, l ? 1 : 0);
  }
  hipLaunchKernelGGL(head_gemm_kernel, dim3(1024), dim3(256), 0, stream, Y, Wdt, bd);
}

// Round 13
// 35923.380 us; speedup vs baseline: 1.7280x; 1.0138x over previous
//
#include <hip/hip_runtime.h>
#include <cstdint>
#include <cstddef>

#define ZONEOUT 0.1f

typedef __attribute__((ext_vector_type(8))) short bf16x8;
typedef __attribute__((ext_vector_type(4))) float f32x4;
typedef __attribute__((ext_vector_type(4))) unsigned short u16x4;
typedef __attribute__((ext_vector_type(8))) unsigned short u16x8;
typedef __attribute__((ext_vector_type(4))) float float4_;

static constexpr int BB = 16;    // batch
static constexpr int TT = 4096;  // time
static constexpr int DD = 256;   // model dim
static constexpr int UU = 256;   // units
static constexpr int GG = 768;   // 3*UU
static constexpr int STR = 280;  // u16 row stride: 560B = 35*16 (b128-aligned), ~2-way banks
static constexpr int UTS = 72;   // Utail u16 row stride: 144B = 9*16 (aligned)

__device__ __forceinline__ unsigned short f2bf(float f) {
  unsigned int u = __builtin_bit_cast(unsigned int, f);
  u = u + 0x7fffu + ((u >> 16) & 1u);
  return (unsigned short)(u >> 16);
}
__device__ __forceinline__ float bf2f(unsigned short s) {
  unsigned int u = ((unsigned int)s) << 16;
  return __builtin_bit_cast(float, u);
}
__device__ __forceinline__ float sigm(float x) {
  float e = __builtin_amdgcn_exp2f(-1.4426950408889634f * x);
  return __builtin_amdgcn_rcpf(1.0f + e);
}
__device__ __forceinline__ float tanh_(float x) {
  float e = __builtin_amdgcn_exp2f(2.8853900817779268f * x);
  return 1.0f - 2.0f * __builtin_amdgcn_rcpf(1.0f + e);
}

// Workgroup barrier WITHOUT vmcnt(0) drain: LDS-visibility only.
__device__ __forceinline__ void wg_barrier_lds() {
  asm volatile("s_waitcnt lgkmcnt(0)\n\ts_barrier" ::: "memory");
}

// dst[n*K + k] = (bf16) src[k*N + n]
__global__ void transpose_cast_kernel(const float* __restrict__ src,
                                      unsigned short* __restrict__ dst,
                                      int K, int N) {
  int idx = blockIdx.x * blockDim.x + threadIdx.x;
  int total = K * N;
  if (idx < total) {
    int k = idx / N, n = idx - k * N;
    dst[(size_t)n * K + k] = f2bf(src[idx]);
  }
}

// xg[m][u][slot] = (In @ W)[m][g] + b_in[g] (+ b_rec[g] for z,r).  Slot 3 unused.
__launch_bounds__(256, 2)
__global__ void gates_gemm_kernel(const float* __restrict__ In,          // [M][256] fp32
                                  const unsigned short* __restrict__ Wt, // [768][256] bf16
                                  const float* __restrict__ bin,         // [768]
                                  const float* __restrict__ brec,        // [768]
                                  unsigned short* __restrict__ xgp) {    // [M][256][4] bf16
  __shared__ unsigned short Asm[64 * STR];
  __shared__ unsigned short Bsm[64 * STR];
  const int m0 = blockIdx.x * 64;
  const int n0 = blockIdx.y * 64;
  const int tid = threadIdx.x;
  {
    int row = tid >> 2, cb = (tid & 3) * 64;
    const float* src = In + (size_t)(m0 + row) * DD + cb;
#pragma unroll
    for (int i = 0; i < 16; ++i) {
      float4_ v = *(const float4_*)(src + i * 4);
      u16x4 o;
      o.x = f2bf(v.x); o.y = f2bf(v.y); o.z = f2bf(v.z); o.w = f2bf(v.w);
      *(u16x4*)(&Asm[row * STR + cb + i * 4]) = o;
    }
  }
  {
#pragma unroll
    for (int i = 0; i < 8; ++i) {
      int c = i * 256 + tid;
      int row = c >> 5, part = c & 31;
      u16x8 v = *(const u16x8*)(Wt + (size_t)(n0 + row) * 256 + part * 8);
      *(u16x8*)(&Bsm[row * STR + part * 8]) = v;
    }
  }
  __syncthreads();
  const int w = tid >> 6, l = tid & 63, lr = l & 15, lg = l >> 4;
  f32x4 acc[4] = {};
#pragma unroll
  for (int k0 = 0; k0 < 8; ++k0) {
    bf16x8 a = *(const bf16x8*)(&Asm[(16 * w + lr) * STR + 32 * k0 + 8 * lg]);
#pragma unroll
    for (int ti = 0; ti < 4; ++ti) {
      bf16x8 b = *(const bf16x8*)(&Bsm[(16 * ti + lr) * STR + 32 * k0 + 8 * lg]);
      acc[ti] = __builtin_amdgcn_mfma_f32_16x16x32_bf16(a, b, acc[ti], 0, 0, 0);
    }
  }
#pragma unroll
  for (int ti = 0; ti < 4; ++ti) {
    int gcol = n0 + 16 * ti + lr;
    int u = gcol & 255, slot = gcol >> 8;
    float bias = bin[gcol] + (slot < 2 ? brec[gcol] : 0.0f);
#pragma unroll
    for (int r = 0; r < 4; ++r) {
      int m = m0 + 16 * w + 4 * lg + r;
      xgp[(size_t)m * 1024 + u * 4 + slot] = f2bf(acc[ti][r] + bias);
    }
  }
}

// In-place dense head: Y[m][:] = (bf16)Y[m][:] @ Wd + bd.
__launch_bounds__(256, 2)
__global__ void head_gemm_kernel(float* __restrict__ y,
                                 const unsigned short* __restrict__ Wdt,
                                 const float* __restrict__ bd) {
  __shared__ unsigned short Asm[64 * STR];
  const int m0 = blockIdx.x * 64;
  const int tid = threadIdx.x;
  {
    int row = tid >> 2, cb = (tid & 3) * 64;
    const float* src = y + (size_t)(m0 + row) * UU + cb;
#pragma unroll
    for (int i = 0; i < 16; ++i) {
      float4_ v = *(const float4_*)(src + i * 4);
      u16x4 o;
      o.x = f2bf(v.x); o.y = f2bf(v.y); o.z = f2bf(v.z); o.w = f2bf(v.w);
      *(u16x4*)(&Asm[row * STR + cb + i * 4]) = o;
    }
  }
  __syncthreads();
  const int w = tid >> 6, l = tid & 63, lr = l & 15, lg = l >> 4;
  f32x4 acc[16] = {};
#pragma unroll
  for (int k0 = 0; k0 < 8; ++k0) {
    bf16x8 a = *(const bf16x8*)(&Asm[(16 * w + lr) * STR + 32 * k0 + 8 * lg]);
#pragma unroll
    for (int ti = 0; ti < 16; ++ti) {
      bf16x8 b = *(const bf16x8*)(Wdt + (size_t)(16 * ti + lr) * 256 + 32 * k0 + 8 * lg);
      acc[ti] = __builtin_amdgcn_mfma_f32_16x16x32_bf16(a, b, acc[ti], 0, 0, 0);
    }
  }
#pragma unroll
  for (int ti = 0; ti < 16; ++ti) {
    int n = 16 * ti + lr;
    float bias = bd[n];
#pragma unroll
    for (int r = 0; r < 4; ++r) {
      int m = m0 + 16 * w + 4 * lg + r;
      y[(size_t)m * DD + n] = acc[ti][r] + bias;
    }
  }
}

// Sequential GRU scan: ONE workgroup of 256 threads = 4 waves, 1 wave/SIMD.
// Round-12 base (248 arch VGPR + 240 AGPR resident, all-intrinsic MFMA,
// absmax 0.0156) restructured for ILP: per-step order is
//   MFMA(tri0) MFMA(tri1) gate(tri0) MFMA(tri2) gate(tri1) MFMA(tri3)
//   gate(tri2) gate(tri3)
// so each gate phase issues while later tri's MFMAs occupy the matrix pipe
// (1 wave/SIMD has no TLP — overlap must come from instruction order).
// Round 12's order (all MFMA, then all gates) ran the pipes serialized:
// 21.5% MFMA + 40% VALU on the active CU, 7150 cyc/step vs the 1860-cyc
// MFMA floor (384 MFMAs/step at 3377 FLOP/cyc/CU).
__global__ void __attribute__((amdgpu_flat_work_group_size(256, 256), amdgpu_waves_per_eu(1, 1)))
gru_scan_kernel(const unsigned short* __restrict__ xgp, // [B*T][256][4] bf16
                const unsigned short* __restrict__ Ut,  // [768][256] bf16
                const float* __restrict__ brec,         // [768]
                const float* __restrict__ h0,           // [256]
                float* __restrict__ y,                  // [B][T][256] fp32
                int resid) {
  __shared__ unsigned short Utail[GG * UTS];     // k 192..255
  __shared__ unsigned short Hsm[2][BB * STR];    // double-buffered h (bf16)

  const int tid = threadIdx.x;
  const int w = tid >> 6;       // wave 0..3, owns units [64w, 64w+64)
  const int l = tid & 63;
  const int lr = l & 15;
  const int lg = l >> 4;

  // Stage U k-tail (768 rows x 64 bf16) with 256 threads
#pragma unroll
  for (int i = 0; i < 24; ++i) {
    int c = i * 256 + tid;
    int row = c >> 3, part = c & 7;
    u16x8 v = *(const u16x8*)(Ut + (size_t)row * 256 + 192 + part * 8);
    *(u16x8*)(&Utail[row * UTS + part * 8]) = v;
  }

  // U k0..4 -> AGPRs (60 x f32x4 = 240 regs); U k5 -> arch VGPRs (48).
  f32x4 ufr[4][3][5];
  f32x4 ufr5[4][3];
  float bias_h[4];
#pragma unroll
  for (int tri = 0; tri < 4; ++tri) {
    int u = 64 * w + 16 * tri + lr;
    bias_h[tri] = brec[512 + u];
#pragma unroll
    for (int g = 0; g < 3; ++g) {
      int n = g * 256 + u;
#pragma unroll
      for (int k0 = 0; k0 < 5; ++k0) {
        ufr[tri][g][k0] = *(const f32x4*)(Ut + (size_t)n * 256 + 32 * k0 + 8 * lg);
        asm volatile("" : "+a"(ufr[tri][g][k0]));  // place in AGPR (intrinsic reads AV-class)
      }
      ufr5[tri][g] = *(const f32x4*)(Ut + (size_t)n * 256 + 32 * 5 + 8 * lg);
      asm volatile("" : "+v"(ufr5[tri][g]));       // keep in arch VGPR
    }
  }

  // h init (broadcast h0) into buffer 0
  float hprev[4][4];
#pragma unroll
  for (int tri = 0; tri < 4; ++tri) {
    int u = 64 * w + 16 * tri + lr;
    float hv = h0[u];
#pragma unroll
    for (int r = 0; r < 4; ++r) {
      hprev[tri][r] = hv;
      Hsm[0][(4 * lg + r) * STR + u] = f2bf(hv);
    }
  }

  // Per-lane xg byte offsets (tri adds 128B)
  unsigned xoff[4];
#pragma unroll
  for (int r = 0; r < 4; ++r)
    xoff[r] = (unsigned)((((4 * lg + r) * TT) * 1024 + (64 * w + lr) * 4) * 2);

  // Prefetch xg(0)
  u16x4 xv[4][4];
#pragma unroll
  for (int tri = 0; tri < 4; ++tri)
#pragma unroll
    for (int r = 0; r < 4; ++r)
      xv[tri][r] = *(const u16x4*)((const char*)xgp + xoff[r] + tri * 128);
  wg_barrier_lds();

  for (int t = 0; t < TT; ++t) {
    const unsigned short* cur = &Hsm[t & 1][0];
    unsigned short* nxt = &Hsm[(t + 1) & 1][0];
    const unsigned tnadd = (t < TT - 1) ? 2048u : 0u;

    // Residual prefetch (drains under the MFMA blocks)
    float ypref[4][4];
    if (resid) {
#pragma unroll
      for (int tri = 0; tri < 4; ++tri) {
        int u = 64 * w + 16 * tri + lr;
#pragma unroll
        for (int r = 0; r < 4; ++r) {
          int b = 4 * lg + r;
          ypref[tri][r] = y[((size_t)b * TT + t) * UU + u];
        }
      }
    }

    f32x4 acc[4][3] = {};

    // --- per-tri MFMA block: completes acc[tri] (k0..7) ---
#define MFMA_TRI(tri)                                                          \
    {                                                                          \
      _Pragma("unroll")                                                        \
      for (int k0 = 0; k0 < 5; ++k0) {                                         \
        bf16x8 a = *(const bf16x8*)(&cur[lr * STR + 32 * k0 + 8 * lg]);        \
        _Pragma("unroll")                                                      \
        for (int g = 0; g < 3; ++g)                                            \
          acc[tri][g] = __builtin_amdgcn_mfma_f32_16x16x32_bf16(               \
              a, __builtin_bit_cast(bf16x8, ufr[tri][g][k0]), acc[tri][g], 0, 0, 0); \
      }                                                                        \
      {                                                                        \
        bf16x8 a = *(const bf16x8*)(&cur[lr * STR + 32 * 5 + 8 * lg]);         \
        _Pragma("unroll")                                                      \
        for (int g = 0; g < 3; ++g)                                            \
          acc[tri][g] = __builtin_amdgcn_mfma_f32_16x16x32_bf16(               \
              a, __builtin_bit_cast(bf16x8, ufr5[tri][g]), acc[tri][g], 0, 0, 0); \
      }                                                                        \
      _Pragma("unroll")                                                        \
      for (int k0 = 6; k0 < 8; ++k0) {                                         \
        bf16x8 a = *(const bf16x8*)(&cur[lr * STR + 32 * k0 + 8 * lg]);        \
        _Pragma("unroll")                                                      \
        for (int g = 0; g < 3; ++g) {                                          \
          int n = g * 256 + 64 * w + 16 * (tri) + lr;                          \
          bf16x8 bfr = *(const bf16x8*)(&Utail[n * UTS + (k0 - 6) * 32 + 8 * lg]); \
          acc[tri][g] = __builtin_amdgcn_mfma_f32_16x16x32_bf16(a, bfr, acc[tri][g], 0, 0, 0); \
        }                                                                      \
      }                                                                        \
    }

    // --- per-tri gate block: consumes acc[tri], updates h, writes y ---
#define GATE_TRI(tri)                                                          \
    {                                                                          \
      int u = 64 * w + 16 * (tri) + lr;                                        \
      _Pragma("unroll")                                                        \
      for (int r = 0; r < 4; ++r) {                                            \
        int b = 4 * lg + r;                                                    \
        u16x4 xvv = xv[tri][r];                                                \
        xv[tri][r] = *(const u16x4*)((const char*)xgp + xoff[r] + (tri) * 128 + tnadd); \
        float xz = bf2f(xvv.x), xr = bf2f(xvv.y), xh = bf2f(xvv.z);            \
        float h = hprev[tri][r];                                               \
        float z = sigm(xz + acc[tri][0][r]);                                   \
        float rg = sigm(xr + acc[tri][1][r]);                                  \
        float hh = tanh_(xh + rg * (acc[tri][2][r] + bias_h[tri]));            \
        float cand = hh + z * (h - hh);                                        \
        float hnew = cand + ZONEOUT * (h - cand);                              \
        hprev[tri][r] = hnew;                                                  \
        nxt[b * STR + u] = f2bf(hnew);                                         \
        float ov = cand;                                                       \
        if (resid) ov += ypref[tri][r];                                        \
        y[((size_t)b * TT + t) * UU + u] = ov;                                 \
      }                                                                        \
    }

    // Pipelined order: gate(tri) issues while tri+2's MFMAs fill the pipe.
    MFMA_TRI(0)
    MFMA_TRI(1)
    GATE_TRI(0)
    MFMA_TRI(2)
    GATE_TRI(1)
    MFMA_TRI(3)
    GATE_TRI(2)
    GATE_TRI(3)

#undef MFMA_TRI
#undef GATE_TRI

#pragma unroll
    for (int r = 0; r < 4; ++r) xoff[r] += 2048u;
    wg_barrier_lds();
  }
}

extern "C" void kernel_launch(void* const* d_in, const int* in_sizes, int n_in,
                              void* d_out, int out_size, void* d_ws, size_t ws_size,
                              hipStream_t stream) {
  const float* x = (const float*)d_in[0];
  const float* W[3]  = {(const float*)d_in[1], (const float*)d_in[5], (const float*)d_in[9]};
  const float* Um[3] = {(const float*)d_in[2], (const float*)d_in[6], (const float*)d_in[10]};
  const float* bm[3] = {(const float*)d_in[3], (const float*)d_in[7], (const float*)d_in[11]};
  const float* h0m[3] = {(const float*)d_in[4], (const float*)d_in[8], (const float*)d_in[12]};
  const float* Wd = (const float*)d_in[13];
  const float* bd = (const float*)d_in[14];
  float* Y = (float*)d_out;

  char* ws = (char*)d_ws;
  unsigned short* xgp = (unsigned short*)ws;  // [65536][256][4] bf16 = 134,217,728 B
  size_t off = (size_t)65536 * 1024 * 2;
  unsigned short* Ut[3];
  unsigned short* Wt[3];
  for (int l = 0; l < 3; ++l) { Ut[l] = (unsigned short*)(ws + off); off += (size_t)768 * 256 * 2; }
  for (int l = 0; l < 3; ++l) { Wt[l] = (unsigned short*)(ws + off); off += (size_t)768 * 256 * 2; }
  unsigned short* Wdt = (unsigned short*)(ws + off); off += (size_t)256 * 256 * 2;

  const int tgrid = (768 * 256 + 255) / 256;
  for (int l = 0; l < 3; ++l) {
    hipLaunchKernelGGL(transpose_cast_kernel, dim3(tgrid), dim3(256), 0, stream, Um[l], Ut[l], 256, 768);
    hipLaunchKernelGGL(transpose_cast_kernel, dim3(tgrid), dim3(256), 0, stream, W[l], Wt[l], 256, 768);
  }
  hipLaunchKernelGGL(transpose_cast_kernel, dim3((256 * 256 + 255) / 256), dim3(256), 0, stream,
                     Wd, Wdt, 256, 256);

  for (int l = 0; l < 3; ++l) {
    const float* in_l = (l == 0) ? x : Y;
    hipLaunchKernelGGL(gates_gemm_kernel, dim3(1024, 12), dim3(256), 0, stream,
                       in_l, Wt[l], bm[l], bm[l] + 768, xgp);
    hipLaunchKernelGGL(gru_scan_kernel, dim3(1), dim3(256), 0, stream,
                       xgp, Ut[l], bm[l] + 768, h0m[l], Y, l ? 1 : 0);
  }
  hipLaunchKernelGGL(head_gemm_kernel, dim3(1024), dim3(256), 0, stream, Y, Wdt, bd);
}